// Round 11
// baseline (115.121 us; speedup 1.0000x reference)
//
#include <hip/hip_runtime.h>

constexpr int B = 8;
constexpr int A = 49104;
constexpr int C = 90;
constexpr int M = 32;
constexpr float EPS_CLIP = 1e-4f;
constexpr float LN2 = 0.6931471805599453f;

constexpr int TPB = 256;
constexpr int N4_TOT = B * A * C / 4;               // 8,838,720 float4 total
constexpr int N4_IMG = A * C / 4;                   // 1,104,840 float4 per image
constexpr int SL4 = 4096;                           // float4 per stream slice (64 KB)
constexpr int NSTREAM = (N4_TOT + SL4 - 1) / SL4;   // 2158
constexpr int APT = 4;                              // anchors per thread
constexpr int AB_ANCH = TPB * APT;                  // 1024 anchors per anchor-block
constexpr int ABPI = (A + AB_ANCH - 1) / AB_ANCH;   // 48 anchor-blocks per image
constexpr int NANCH = ABPI * B;                     // 384
constexpr int NTOTB = NSTREAM + NANCH;              // 2542 blocks

typedef float f32x4 __attribute__((ext_vector_type(4)));

// accum (d_ws floats): [0..B) S (log2 domain), [B..2B) corr, [2B..3B) reg_sum,
//                      [3B..4B) pos_cnt, [36] completion counter (int alias)

__device__ __forceinline__ float clampp(float v) {
    return fminf(fmaxf(v, EPS_CLIP), 1.f - EPS_CLIP);   // v_med3_f32
}

__device__ __forceinline__ float neg4(f32x4 v) {
    float s = 0.f;
#pragma unroll
    for (int j = 0; j < 4; ++j) {
        const float p = clampp(v[j]);
        s = fmaf(p * p, __log2f(1.f - p), s);
    }
    return s;
}

__global__ __launch_bounds__(TPB) void focal_main_kernel(
    const float* __restrict__ cls,   // [B, A, C]
    const float* __restrict__ reg,   // [B, A, 4]
    const float* __restrict__ anc,   // [A, 4]
    const float* __restrict__ ann,   // [B, M, 5]
    float* __restrict__ accum,
    float* __restrict__ out)
{
    __shared__ float s_ann[M * 5];
    __shared__ float s_red[3][TPB / 64];
    __shared__ int   s_list[AB_ANCH];
    __shared__ int   s_cnt;
    __shared__ int   s_last;

    const int t    = threadIdx.x;
    const int wid  = t >> 6;
    const int lane = t & 63;
    const int blk  = blockIdx.x;

    if (blk < NSTREAM) {
        // ============ Stream blocks (grid front: saturate reads from t=0) ============
        const f32x4* __restrict__ cls4 = reinterpret_cast<const f32x4*>(cls);
        const int sbase = blk * SL4;
        const int nsl   = min(SL4, N4_TOT - sbase);
        const int img0  = sbase / N4_IMG;
        const int imgL  = (sbase + nsl - 1) / N4_IMG;

        float acc0 = 0.f, acc1 = 0.f;
        if (img0 == imgL) {
            const f32x4* p = cls4 + sbase + t;
            int i = t;
            float accA = 0.f, accB = 0.f;
            for (; i + 7 * TPB < nsl; i += 8 * TPB) {
                f32x4 v[8];
#pragma unroll
                for (int k = 0; k < 8; ++k) v[k] = p[k * TPB];
                p += 8 * TPB;
#pragma unroll
                for (int k = 0; k < 8; ++k) {
                    if (k & 1) accB += neg4(v[k]); else accA += neg4(v[k]);
                }
            }
            for (; i < nsl; i += TPB) { accA += neg4(*p); p += TPB; }
            acc0 = accA + accB;
        } else {
            // image-boundary slice (7 of 2158)
            const int split = (img0 + 1) * N4_IMG;
            for (int i = t; i < nsl; i += TPB) {
                const float s = neg4(cls4[sbase + i]);
                if (sbase + i < split) acc0 += s; else acc1 += s;
            }
        }

        float w0 = acc0, w1 = acc1;
        for (int off = 32; off; off >>= 1) {
            w0 += __shfl_down(w0, off);
            w1 += __shfl_down(w1, off);
        }
        if (lane == 0) { s_red[0][wid] = w0; s_red[1][wid] = w1; }
        __syncthreads();
        if (t == 0) {
            float a0 = 0.f, a1 = 0.f;
            for (int w = 0; w < TPB / 64; ++w) { a0 += s_red[0][w]; a1 += s_red[1][w]; }
            atomicAdd(&accum[img0], a0);
            if (imgL != img0) atomicAdd(&accum[imgL], a1);
        }
    } else {
        // ============ Anchor blocks (grid tail: hide in stream wind-down) ============
        const int ablk  = blk - NSTREAM;
        const int b     = ablk / ABPI;
        const int abase = (ablk - b * ABPI) * AB_ANCH;

        if (t < M * 5) s_ann[t] = ann[b * M * 5 + t];
        if (t == 0) s_cnt = 0;
        __syncthreads();

        float corr = 0.f, reg_sum = 0.f, pos_cnt = 0.f;

        float4 ab4[APT];
        float  awk[APT], ahk[APT], areaA[APT], best[APT];
        int    argm[APT];
        bool   act[APT];
#pragma unroll
        for (int k = 0; k < APT; ++k) {
            const int a = abase + t + k * TPB;
            act[k] = (a < A);
            ab4[k] = act[k] ? reinterpret_cast<const float4*>(anc)[a]
                            : make_float4(0.f, 0.f, 0.f, 0.f);
            awk[k] = ab4[k].z - ab4[k].x;
            ahk[k] = ab4[k].w - ab4[k].y;
            areaA[k] = awk[k] * ahk[k];
            best[k] = -INFINITY;
            argm[k] = 0;
        }

        for (int m = 0; m < M; ++m) {
            const float bx1 = s_ann[m * 5 + 0];
            const float by1 = s_ann[m * 5 + 1];
            const float bx2 = s_ann[m * 5 + 2];
            const float by2 = s_ann[m * 5 + 3];
            const float lab = s_ann[m * 5 + 4];
            const float areaB = (bx2 - bx1) * (by2 - by1);
            const bool  vgt = (lab != -1.0f);
#pragma unroll
            for (int k = 0; k < APT; ++k) {
                float iw = fminf(ab4[k].z, bx2) - fmaxf(ab4[k].x, bx1);
                float ih = fminf(ab4[k].w, by2) - fmaxf(ab4[k].y, by1);
                iw = fmaxf(iw, 0.f);
                ih = fmaxf(ih, 0.f);
                const float inter = iw * ih;
                const float ua = fmaxf(areaA[k] + areaB - inter, 1e-8f);
                const float iou = inter / ua;
                const float val = vgt ? iou : -1.0f;
                if (val > best[k]) { best[k] = val; argm[k] = m; }   // first argmax
            }
        }

#pragma unroll
        for (int k = 0; k < APT; ++k) {
            if (!act[k]) continue;
            const int a = abase + t + k * TPB;
            if (best[k] >= 0.5f) {
                pos_cnt += 1.f;
                const int am = argm[k];
                const float gx1 = s_ann[am * 5 + 0];
                const float gy1 = s_ann[am * 5 + 1];
                const float gx2 = s_ann[am * 5 + 2];
                const float gy2 = s_ann[am * 5 + 3];
                const float acx = ab4[k].x + 0.5f * awk[k];
                const float acy = ab4[k].y + 0.5f * ahk[k];
                const float gw0 = gx2 - gx1;
                const float gh0 = gy2 - gy1;
                const float gcx = gx1 + 0.5f * gw0;
                const float gcy = gy1 + 0.5f * gh0;
                const float gw = fmaxf(gw0, 1.f);
                const float gh = fmaxf(gh0, 1.f);
                const float4 rp = reinterpret_cast<const float4*>(reg)[(size_t)b * A + a];
                const float rt0 = (gcx - acx) / awk[k] * 10.f;
                const float rt1 = (gcy - acy) / ahk[k] * 10.f;
                const float rt2 = __logf(gw / awk[k]) * 5.f;
                const float rt3 = __logf(gh / ahk[k]) * 5.f;
                const float d0 = fabsf(rt0 - rp.x);
                const float d1 = fabsf(rt1 - rp.y);
                const float d2 = fabsf(rt2 - rp.z);
                const float d3 = fabsf(rt3 - rp.w);
                auto sl1 = [](float d) {
                    return (d <= (1.f / 9.f)) ? 4.5f * d * d : d - (0.5f / 9.f);
                };
                reg_sum += sl1(d0) + sl1(d1) + sl1(d2) + sl1(d3);

                const int cidx = (int)s_ann[am * 5 + 4];
                const float p = clampp(cls[((size_t)b * A + a) * C + cidx]);
                corr += 0.75f * LN2 * (p * p * __log2f(1.f - p))      // cancel streamed term
                      + 0.25f * (1.f - p) * (1.f - p) * (-__logf(p)); // true positive term
            } else if (best[k] >= 0.4f) {
                const int slot = atomicAdd(&s_cnt, 1);
                s_list[slot] = t + k * TPB;
            }
        }
        __syncthreads();

        // wave-cooperative coalesced row sums for ignore anchors (L3-warm by now)
        const int cnt = s_cnt;
        for (int i = wid; i < cnt; i += TPB / 64) {
            const int aidx = s_list[i];
            const float* row = cls + ((size_t)b * A + abase + aidx) * (size_t)C;
            float s = 0.f;
            if (lane < C) {
                const float p = clampp(row[lane]);
                s = p * p * __log2f(1.f - p);
            }
            if (lane + 64 < C) {
                const float p = clampp(row[lane + 64]);
                s = fmaf(p * p, __log2f(1.f - p), s);
            }
            for (int off = 32; off; off >>= 1) s += __shfl_down(s, off);
            if (lane == 0) corr += 0.75f * LN2 * s;
        }

        float v0 = corr, v1 = reg_sum, v2 = pos_cnt;
        for (int off = 32; off; off >>= 1) {
            v0 += __shfl_down(v0, off);
            v1 += __shfl_down(v1, off);
            v2 += __shfl_down(v2, off);
        }
        if (lane == 0) { s_red[0][wid] = v0; s_red[1][wid] = v1; s_red[2][wid] = v2; }
        __syncthreads();
        if (t == 0) {
            float a0 = 0.f, a1 = 0.f, a2 = 0.f;
            for (int w = 0; w < TPB / 64; ++w) {
                a0 += s_red[0][w]; a1 += s_red[1][w]; a2 += s_red[2][w];
            }
            atomicAdd(&accum[B + b],     a0);
            atomicAdd(&accum[2 * B + b], a1);
            atomicAdd(&accum[3 * B + b], a2);
        }
    }

    // ================= Epilogue: last block finalizes =================
    if (t == 0) {
        __threadfence();                                  // publish our atomics
        int* ctr = reinterpret_cast<int*>(accum + 36);
        const int done = atomicAdd(ctr, 1);
        s_last = (done == NTOTB - 1) ? 1 : 0;
    }
    __syncthreads();
    if (s_last) {
        float cls_l = 0.f, reg_l = 0.f;
        if (t < B) {
            bool has = false;
            for (int m = 0; m < M; ++m)
                has = has || (ann[t * M * 5 + m * 5 + 4] != -1.0f);
            // coherent (device-scope) reads of the accumulators
            const float S    = atomicAdd(&accum[t],         0.f);
            const float corr = atomicAdd(&accum[B + t],     0.f);
            const float rs   = atomicAdd(&accum[2 * B + t], 0.f);
            const float np   = atomicAdd(&accum[3 * B + t], 0.f);
            const float cls_sum = -0.75f * LN2 * S + corr;
            cls_l = has ? cls_sum / fmaxf(np, 1.f) : 0.f;
            reg_l = (has && np > 0.f) ? rs / fmaxf(np * 4.f, 1.f) : 0.f;
        }
        if (t < 64) {
            for (int off = 4; off; off >>= 1) {
                cls_l += __shfl_down(cls_l, off);
                reg_l += __shfl_down(reg_l, off);
            }
            if (t == 0) {
                out[0] = cls_l * (1.f / B);
                out[1] = reg_l * (1.f / B);
            }
        }
    }
}

extern "C" void kernel_launch(void* const* d_in, const int* in_sizes, int n_in,
                              void* d_out, int out_size, void* d_ws, size_t ws_size,
                              hipStream_t stream) {
    const float* cls = (const float*)d_in[0];
    const float* reg = (const float*)d_in[1];
    const float* anc = (const float*)d_in[2];
    const float* ann = (const float*)d_in[3];
    float* out = (float*)d_out;
    float* accum = (float*)d_ws;

    (void)hipMemsetAsync(accum, 0, 40 * sizeof(float), stream);

    focal_main_kernel<<<dim3(NTOTB), TPB, 0, stream>>>(cls, reg, anc, ann, accum, out);
}

// Round 12
// 66.518 us; speedup vs baseline: 1.7307x; 1.7307x over previous
//
#include <hip/hip_runtime.h>

constexpr int B = 8;
constexpr int A = 49104;
constexpr int C = 90;
constexpr int M = 32;
constexpr float EPS_CLIP = 1e-4f;
constexpr float LN2 = 0.6931471805599453f;

constexpr int TPB = 256;
constexpr int N4_TOT = B * A * C / 4;               // 8,838,720 float4 total
constexpr int N4_IMG = A * C / 4;                   // 1,104,840 float4 per image
constexpr int SL4 = 4096;                           // float4 per stream slice (64 KB)
constexpr int NSTREAM = (N4_TOT + SL4 - 1) / SL4;   // 2158
constexpr int APT = 4;                              // anchors per thread
constexpr int AB_ANCH = TPB * APT;                  // 1024 anchors per anchor-block
constexpr int ABPI = (A + AB_ANCH - 1) / AB_ANCH;   // 48 anchor-blocks per image
constexpr int NANCH = ABPI * B;                     // 384
constexpr int NTOTB = NSTREAM + NANCH;              // 2542 blocks

typedef float f32x4 __attribute__((ext_vector_type(4)));

// accum (d_ws): [0..B) S (log2 domain), [B..2B) corr, [2B..3B) reg_sum, [3B..4B) pos_cnt

__device__ __forceinline__ float clampp(float v) {
    return fminf(fmaxf(v, EPS_CLIP), 1.f - EPS_CLIP);   // v_med3_f32
}

__device__ __forceinline__ float neg4(f32x4 v) {
    float s = 0.f;
#pragma unroll
    for (int j = 0; j < 4; ++j) {
        const float p = clampp(v[j]);
        s = fmaf(p * p, __log2f(1.f - p), s);
    }
    return s;
}

__global__ __launch_bounds__(TPB) void focal_main_kernel(
    const float* __restrict__ cls,   // [B, A, C]
    const float* __restrict__ reg,   // [B, A, 4]
    const float* __restrict__ anc,   // [A, 4]
    const float* __restrict__ ann,   // [B, M, 5]
    float* __restrict__ accum)
{
    __shared__ float s_ann[M * 5];
    __shared__ float s_red[3][TPB / 64];
    __shared__ int   s_list[AB_ANCH];
    __shared__ int   s_cnt;

    const int t    = threadIdx.x;
    const int wid  = t >> 6;
    const int lane = t & 63;
    const int blk  = blockIdx.x;

    if (blk < NSTREAM) {
        // ============ Stream blocks (grid front: saturate reads from t=0) ============
        const f32x4* __restrict__ cls4 = reinterpret_cast<const f32x4*>(cls);
        const int sbase = blk * SL4;
        const int nsl   = min(SL4, N4_TOT - sbase);
        const int img0  = sbase / N4_IMG;
        const int imgL  = (sbase + nsl - 1) / N4_IMG;

        float acc0 = 0.f, acc1 = 0.f;
        if (img0 == imgL) {
            const f32x4* p = cls4 + sbase + t;
            int i = t;
            float accA = 0.f, accB = 0.f;
            for (; i + 7 * TPB < nsl; i += 8 * TPB) {
                f32x4 v[8];
#pragma unroll
                for (int k = 0; k < 8; ++k) v[k] = p[k * TPB];
                p += 8 * TPB;
#pragma unroll
                for (int k = 0; k < 8; ++k) {
                    if (k & 1) accB += neg4(v[k]); else accA += neg4(v[k]);
                }
            }
            for (; i < nsl; i += TPB) { accA += neg4(*p); p += TPB; }
            acc0 = accA + accB;
        } else {
            // image-boundary slice (7 of 2158)
            const int split = (img0 + 1) * N4_IMG;
            for (int i = t; i < nsl; i += TPB) {
                const float s = neg4(cls4[sbase + i]);
                if (sbase + i < split) acc0 += s; else acc1 += s;
            }
        }

        float w0 = acc0, w1 = acc1;
        for (int off = 32; off; off >>= 1) {
            w0 += __shfl_down(w0, off);
            w1 += __shfl_down(w1, off);
        }
        if (lane == 0) { s_red[0][wid] = w0; s_red[1][wid] = w1; }
        __syncthreads();
        if (t == 0) {
            float a0 = 0.f, a1 = 0.f;
            for (int w = 0; w < TPB / 64; ++w) { a0 += s_red[0][w]; a1 += s_red[1][w]; }
            atomicAdd(&accum[img0], a0);
            if (imgL != img0) atomicAdd(&accum[imgL], a1);
        }
    } else {
        // ============ Anchor blocks (grid tail: run L3-warm in stream wind-down) ============
        const int ablk  = blk - NSTREAM;
        const int b     = ablk / ABPI;
        const int abase = (ablk - b * ABPI) * AB_ANCH;

        if (t < M * 5) s_ann[t] = ann[b * M * 5 + t];
        if (t == 0) s_cnt = 0;
        __syncthreads();

        float corr = 0.f, reg_sum = 0.f, pos_cnt = 0.f;

        float4 ab4[APT];
        float  awk[APT], ahk[APT], areaA[APT], best[APT];
        int    argm[APT];
        bool   act[APT];
#pragma unroll
        for (int k = 0; k < APT; ++k) {
            const int a = abase + t + k * TPB;
            act[k] = (a < A);
            ab4[k] = act[k] ? reinterpret_cast<const float4*>(anc)[a]
                            : make_float4(0.f, 0.f, 0.f, 0.f);
            awk[k] = ab4[k].z - ab4[k].x;
            ahk[k] = ab4[k].w - ab4[k].y;
            areaA[k] = awk[k] * ahk[k];
            best[k] = -INFINITY;
            argm[k] = 0;
        }

        for (int m = 0; m < M; ++m) {
            const float bx1 = s_ann[m * 5 + 0];
            const float by1 = s_ann[m * 5 + 1];
            const float bx2 = s_ann[m * 5 + 2];
            const float by2 = s_ann[m * 5 + 3];
            const float lab = s_ann[m * 5 + 4];
            const float areaB = (bx2 - bx1) * (by2 - by1);
            const bool  vgt = (lab != -1.0f);
#pragma unroll
            for (int k = 0; k < APT; ++k) {
                float iw = fminf(ab4[k].z, bx2) - fmaxf(ab4[k].x, bx1);
                float ih = fminf(ab4[k].w, by2) - fmaxf(ab4[k].y, by1);
                iw = fmaxf(iw, 0.f);
                ih = fmaxf(ih, 0.f);
                const float inter = iw * ih;
                const float ua = fmaxf(areaA[k] + areaB - inter, 1e-8f);
                const float iou = inter / ua;
                const float val = vgt ? iou : -1.0f;
                if (val > best[k]) { best[k] = val; argm[k] = m; }   // first argmax
            }
        }

#pragma unroll
        for (int k = 0; k < APT; ++k) {
            if (!act[k]) continue;
            const int a = abase + t + k * TPB;
            if (best[k] >= 0.5f) {
                pos_cnt += 1.f;
                const int am = argm[k];
                const float gx1 = s_ann[am * 5 + 0];
                const float gy1 = s_ann[am * 5 + 1];
                const float gx2 = s_ann[am * 5 + 2];
                const float gy2 = s_ann[am * 5 + 3];
                const float acx = ab4[k].x + 0.5f * awk[k];
                const float acy = ab4[k].y + 0.5f * ahk[k];
                const float gw0 = gx2 - gx1;
                const float gh0 = gy2 - gy1;
                const float gcx = gx1 + 0.5f * gw0;
                const float gcy = gy1 + 0.5f * gh0;
                const float gw = fmaxf(gw0, 1.f);
                const float gh = fmaxf(gh0, 1.f);
                const float4 rp = reinterpret_cast<const float4*>(reg)[(size_t)b * A + a];
                const float rt0 = (gcx - acx) / awk[k] * 10.f;
                const float rt1 = (gcy - acy) / ahk[k] * 10.f;
                const float rt2 = __logf(gw / awk[k]) * 5.f;
                const float rt3 = __logf(gh / ahk[k]) * 5.f;
                const float d0 = fabsf(rt0 - rp.x);
                const float d1 = fabsf(rt1 - rp.y);
                const float d2 = fabsf(rt2 - rp.z);
                const float d3 = fabsf(rt3 - rp.w);
                auto sl1 = [](float d) {
                    return (d <= (1.f / 9.f)) ? 4.5f * d * d : d - (0.5f / 9.f);
                };
                reg_sum += sl1(d0) + sl1(d1) + sl1(d2) + sl1(d3);

                const int cidx = (int)s_ann[am * 5 + 4];
                const float p = clampp(cls[((size_t)b * A + a) * C + cidx]);
                corr += 0.75f * LN2 * (p * p * __log2f(1.f - p))      // cancel streamed term
                      + 0.25f * (1.f - p) * (1.f - p) * (-__logf(p)); // true positive term
            } else if (best[k] >= 0.4f) {
                const int slot = atomicAdd(&s_cnt, 1);
                s_list[slot] = t + k * TPB;
            }
        }
        __syncthreads();

        // wave-cooperative coalesced row sums for ignore anchors (L3-warm)
        const int cnt = s_cnt;
        for (int i = wid; i < cnt; i += TPB / 64) {
            const int aidx = s_list[i];
            const float* row = cls + ((size_t)b * A + abase + aidx) * (size_t)C;
            float s = 0.f;
            if (lane < C) {
                const float p = clampp(row[lane]);
                s = p * p * __log2f(1.f - p);
            }
            if (lane + 64 < C) {
                const float p = clampp(row[lane + 64]);
                s = fmaf(p * p, __log2f(1.f - p), s);
            }
            for (int off = 32; off; off >>= 1) s += __shfl_down(s, off);
            if (lane == 0) corr += 0.75f * LN2 * s;
        }

        float v0 = corr, v1 = reg_sum, v2 = pos_cnt;
        for (int off = 32; off; off >>= 1) {
            v0 += __shfl_down(v0, off);
            v1 += __shfl_down(v1, off);
            v2 += __shfl_down(v2, off);
        }
        if (lane == 0) { s_red[0][wid] = v0; s_red[1][wid] = v1; s_red[2][wid] = v2; }
        __syncthreads();
        if (t == 0) {
            float a0 = 0.f, a1 = 0.f, a2 = 0.f;
            for (int w = 0; w < TPB / 64; ++w) {
                a0 += s_red[0][w]; a1 += s_red[1][w]; a2 += s_red[2][w];
            }
            atomicAdd(&accum[B + b],     a0);
            atomicAdd(&accum[2 * B + b], a1);
            atomicAdd(&accum[3 * B + b], a2);
        }
    }
}

// ---------------- Finalize (separate kernel; boundary orders the atomics) ----------------
__global__ void focal_finalize_kernel(const float* __restrict__ ann,
                                      const float* __restrict__ accum,
                                      float* __restrict__ out)
{
    const int t = threadIdx.x;
    float cls_l = 0.f, reg_l = 0.f;
    if (t < B) {
        bool has = false;
        for (int m = 0; m < M; ++m)
            has = has || (ann[t * M * 5 + m * 5 + 4] != -1.0f);
        const float S    = accum[t];
        const float corr = accum[B + t];
        const float rs   = accum[2 * B + t];
        const float np   = accum[3 * B + t];
        const float cls_sum = -0.75f * LN2 * S + corr;
        cls_l = has ? cls_sum / fmaxf(np, 1.f) : 0.f;
        reg_l = (has && np > 0.f) ? rs / fmaxf(np * 4.f, 1.f) : 0.f;
    }
    for (int off = 4; off; off >>= 1) {
        cls_l += __shfl_down(cls_l, off);
        reg_l += __shfl_down(reg_l, off);
    }
    if (t == 0) {
        out[0] = cls_l * (1.f / B);
        out[1] = reg_l * (1.f / B);
    }
}

extern "C" void kernel_launch(void* const* d_in, const int* in_sizes, int n_in,
                              void* d_out, int out_size, void* d_ws, size_t ws_size,
                              hipStream_t stream) {
    const float* cls = (const float*)d_in[0];
    const float* reg = (const float*)d_in[1];
    const float* anc = (const float*)d_in[2];
    const float* ann = (const float*)d_in[3];
    float* out = (float*)d_out;
    float* accum = (float*)d_ws;

    (void)hipMemsetAsync(accum, 0, 4 * B * sizeof(float), stream);

    focal_main_kernel<<<dim3(NTOTB), TPB, 0, stream>>>(cls, reg, anc, ann, accum);
    focal_finalize_kernel<<<1, 64, 0, stream>>>(ann, accum, out);
}

// Round 13
// 58.967 us; speedup vs baseline: 1.9523x; 1.1281x over previous
//
#include <hip/hip_runtime.h>

constexpr int B = 8;
constexpr int A = 49104;
constexpr int C = 90;
constexpr int M = 32;
constexpr float EPS_CLIP = 1e-4f;
constexpr float LN2 = 0.6931471805599453f;

constexpr int TPB = 256;
constexpr int N4_TOT = B * A * C / 4;               // 8,838,720 float4 total
constexpr int N4_IMG = A * C / 4;                   // 1,104,840 float4 per image
constexpr int SL4 = 4096;                           // float4 per stream slice (64 KB)
constexpr int NSTREAM = (N4_TOT + SL4 - 1) / SL4;   // 2158
constexpr int APT = 4;                              // anchors per thread
constexpr int AB_ANCH = TPB * APT;                  // 1024 anchors per anchor-block
constexpr int ABPI = (A + AB_ANCH - 1) / AB_ANCH;   // 48 anchor-blocks per image
constexpr int NANCH = ABPI * B;                     // 384
constexpr int NTOTB = NANCH + NSTREAM;              // 2542 blocks

typedef float f32x4 __attribute__((ext_vector_type(4)));

// accum (d_ws floats): [0..B) S (log2 domain), [B..2B) corr, [2B..3B) reg_sum,
//                      [3B..4B) pos_cnt, [36] completion counter (int alias)

__device__ __forceinline__ float clampp(float v) {
    return fminf(fmaxf(v, EPS_CLIP), 1.f - EPS_CLIP);   // v_med3_f32
}

__device__ __forceinline__ float neg4(f32x4 v) {
    float s = 0.f;
#pragma unroll
    for (int j = 0; j < 4; ++j) {
        const float p = clampp(v[j]);
        s = fmaf(p * p, __log2f(1.f - p), s);
    }
    return s;
}

__global__ __launch_bounds__(TPB) void focal_main_kernel(
    const float* __restrict__ cls,   // [B, A, C]
    const float* __restrict__ reg,   // [B, A, 4]
    const float* __restrict__ anc,   // [A, 4]
    const float* __restrict__ ann,   // [B, M, 5]
    float* __restrict__ accum,
    float* __restrict__ out)
{
    __shared__ float s_ann[M * 5];
    __shared__ float s_red[3][TPB / 64];
    __shared__ int   s_list[AB_ANCH];
    __shared__ int   s_cnt;
    __shared__ int   s_last;

    const int t    = threadIdx.x;
    const int wid  = t >> 6;
    const int lane = t & 63;
    const int blk  = blockIdx.x;

    if (blk < NANCH) {
        // ===== Anchor blocks (grid FRONT: co-resident with streams, VALU hides under BW) =====
        const int b     = blk / ABPI;
        const int abase = (blk - b * ABPI) * AB_ANCH;

        if (t < M * 5) s_ann[t] = ann[b * M * 5 + t];
        if (t == 0) s_cnt = 0;
        __syncthreads();

        float corr = 0.f, reg_sum = 0.f, pos_cnt = 0.f;

        float4 ab4[APT];
        float  awk[APT], ahk[APT], areaA[APT], best[APT];
        int    argm[APT];
        bool   act[APT];
#pragma unroll
        for (int k = 0; k < APT; ++k) {
            const int a = abase + t + k * TPB;
            act[k] = (a < A);
            ab4[k] = act[k] ? reinterpret_cast<const float4*>(anc)[a]
                            : make_float4(0.f, 0.f, 0.f, 0.f);
            awk[k] = ab4[k].z - ab4[k].x;
            ahk[k] = ab4[k].w - ab4[k].y;
            areaA[k] = awk[k] * ahk[k];
            best[k] = -INFINITY;
            argm[k] = 0;
        }

        for (int m = 0; m < M; ++m) {
            const float bx1 = s_ann[m * 5 + 0];
            const float by1 = s_ann[m * 5 + 1];
            const float bx2 = s_ann[m * 5 + 2];
            const float by2 = s_ann[m * 5 + 3];
            const float lab = s_ann[m * 5 + 4];
            const float areaB = (bx2 - bx1) * (by2 - by1);
            const bool  vgt = (lab != -1.0f);
#pragma unroll
            for (int k = 0; k < APT; ++k) {
                float iw = fminf(ab4[k].z, bx2) - fmaxf(ab4[k].x, bx1);
                float ih = fminf(ab4[k].w, by2) - fmaxf(ab4[k].y, by1);
                iw = fmaxf(iw, 0.f);
                ih = fmaxf(ih, 0.f);
                const float inter = iw * ih;
                const float ua = fmaxf(areaA[k] + areaB - inter, 1e-8f);
                const float iou = inter / ua;
                const float val = vgt ? iou : -1.0f;
                if (val > best[k]) { best[k] = val; argm[k] = m; }   // first argmax
            }
        }

#pragma unroll
        for (int k = 0; k < APT; ++k) {
            if (!act[k]) continue;
            const int a = abase + t + k * TPB;
            if (best[k] >= 0.5f) {
                pos_cnt += 1.f;
                const int am = argm[k];
                const float gx1 = s_ann[am * 5 + 0];
                const float gy1 = s_ann[am * 5 + 1];
                const float gx2 = s_ann[am * 5 + 2];
                const float gy2 = s_ann[am * 5 + 3];
                const float acx = ab4[k].x + 0.5f * awk[k];
                const float acy = ab4[k].y + 0.5f * ahk[k];
                const float gw0 = gx2 - gx1;
                const float gh0 = gy2 - gy1;
                const float gcx = gx1 + 0.5f * gw0;
                const float gcy = gy1 + 0.5f * gh0;
                const float gw = fmaxf(gw0, 1.f);
                const float gh = fmaxf(gh0, 1.f);
                const float4 rp = reinterpret_cast<const float4*>(reg)[(size_t)b * A + a];
                const float rt0 = (gcx - acx) / awk[k] * 10.f;
                const float rt1 = (gcy - acy) / ahk[k] * 10.f;
                const float rt2 = __logf(gw / awk[k]) * 5.f;
                const float rt3 = __logf(gh / ahk[k]) * 5.f;
                const float d0 = fabsf(rt0 - rp.x);
                const float d1 = fabsf(rt1 - rp.y);
                const float d2 = fabsf(rt2 - rp.z);
                const float d3 = fabsf(rt3 - rp.w);
                auto sl1 = [](float d) {
                    return (d <= (1.f / 9.f)) ? 4.5f * d * d : d - (0.5f / 9.f);
                };
                reg_sum += sl1(d0) + sl1(d1) + sl1(d2) + sl1(d3);

                const int cidx = (int)s_ann[am * 5 + 4];
                const float p = clampp(cls[((size_t)b * A + a) * C + cidx]);
                corr += 0.75f * LN2 * (p * p * __log2f(1.f - p))      // cancel streamed term
                      + 0.25f * (1.f - p) * (1.f - p) * (-__logf(p)); // true positive term
            } else if (best[k] >= 0.4f) {
                const int slot = atomicAdd(&s_cnt, 1);
                s_list[slot] = t + k * TPB;
            }
        }
        __syncthreads();

        // wave-cooperative coalesced row sums for ignore anchors
        const int cnt = s_cnt;
        for (int i = wid; i < cnt; i += TPB / 64) {
            const int aidx = s_list[i];
            const float* row = cls + ((size_t)b * A + abase + aidx) * (size_t)C;
            float s = 0.f;
            if (lane < C) {
                const float p = clampp(row[lane]);
                s = p * p * __log2f(1.f - p);
            }
            if (lane + 64 < C) {
                const float p = clampp(row[lane + 64]);
                s = fmaf(p * p, __log2f(1.f - p), s);
            }
            for (int off = 32; off; off >>= 1) s += __shfl_down(s, off);
            if (lane == 0) corr += 0.75f * LN2 * s;
        }

        float v0 = corr, v1 = reg_sum, v2 = pos_cnt;
        for (int off = 32; off; off >>= 1) {
            v0 += __shfl_down(v0, off);
            v1 += __shfl_down(v1, off);
            v2 += __shfl_down(v2, off);
        }
        if (lane == 0) { s_red[0][wid] = v0; s_red[1][wid] = v1; s_red[2][wid] = v2; }
        __syncthreads();
        if (t == 0) {
            float a0 = 0.f, a1 = 0.f, a2 = 0.f;
            for (int w = 0; w < TPB / 64; ++w) {
                a0 += s_red[0][w]; a1 += s_red[1][w]; a2 += s_red[2][w];
            }
            atomicAdd(&accum[B + b],     a0);
            atomicAdd(&accum[2 * B + b], a1);
            atomicAdd(&accum[3 * B + b], a2);
        }
    } else {
        // ===== Stream blocks (uniform 64 KB contiguous slices) =====
        const int sblk = blk - NANCH;
        const f32x4* __restrict__ cls4 = reinterpret_cast<const f32x4*>(cls);
        const int sbase = sblk * SL4;
        const int nsl   = min(SL4, N4_TOT - sbase);
        const int img0  = sbase / N4_IMG;
        const int imgL  = (sbase + nsl - 1) / N4_IMG;

        float acc0 = 0.f, acc1 = 0.f;
        if (img0 == imgL) {
            const f32x4* p = cls4 + sbase + t;
            int i = t;
            float accA = 0.f, accB = 0.f;
            for (; i + 7 * TPB < nsl; i += 8 * TPB) {
                f32x4 v[8];
#pragma unroll
                for (int k = 0; k < 8; ++k) v[k] = p[k * TPB];
                p += 8 * TPB;
#pragma unroll
                for (int k = 0; k < 8; ++k) {
                    if (k & 1) accB += neg4(v[k]); else accA += neg4(v[k]);
                }
            }
            for (; i < nsl; i += TPB) { accA += neg4(*p); p += TPB; }
            acc0 = accA + accB;
        } else {
            // image-boundary slice (7 of 2158)
            const int split = (img0 + 1) * N4_IMG;
            for (int i = t; i < nsl; i += TPB) {
                const float s = neg4(cls4[sbase + i]);
                if (sbase + i < split) acc0 += s; else acc1 += s;
            }
        }

        float w0 = acc0, w1 = acc1;
        for (int off = 32; off; off >>= 1) {
            w0 += __shfl_down(w0, off);
            w1 += __shfl_down(w1, off);
        }
        if (lane == 0) { s_red[0][wid] = w0; s_red[1][wid] = w1; }
        __syncthreads();
        if (t == 0) {
            float a0 = 0.f, a1 = 0.f;
            for (int w = 0; w < TPB / 64; ++w) { a0 += s_red[0][w]; a1 += s_red[1][w]; }
            atomicAdd(&accum[img0], a0);
            if (imgL != img0) atomicAdd(&accum[imgL], a1);
        }
    }

    // ===== Last-block-done finalize (no fences: vmcnt orders own atomics; =====
    // ===== atomicAdd(p,0) reads are device-scope coherent)                =====
    if (t == 0) {
        asm volatile("s_waitcnt vmcnt(0)" ::: "memory");  // own data atomics complete at L2
        int* ctr = reinterpret_cast<int*>(accum + 36);
        const int done = atomicAdd(ctr, 1);
        s_last = (done == NTOTB - 1) ? 1 : 0;
    }
    __syncthreads();
    if (s_last) {
        float cls_l = 0.f, reg_l = 0.f;
        if (t < B) {
            bool has = false;
            for (int m = 0; m < M; ++m)
                has = has || (ann[t * M * 5 + m * 5 + 4] != -1.0f);
            const float S    = atomicAdd(&accum[t],         0.f);
            const float corr = atomicAdd(&accum[B + t],     0.f);
            const float rs   = atomicAdd(&accum[2 * B + t], 0.f);
            const float np   = atomicAdd(&accum[3 * B + t], 0.f);
            const float cls_sum = -0.75f * LN2 * S + corr;
            cls_l = has ? cls_sum / fmaxf(np, 1.f) : 0.f;
            reg_l = (has && np > 0.f) ? rs / fmaxf(np * 4.f, 1.f) : 0.f;
        }
        if (t < 64) {
            for (int off = 4; off; off >>= 1) {
                cls_l += __shfl_down(cls_l, off);
                reg_l += __shfl_down(reg_l, off);
            }
            if (t == 0) {
                out[0] = cls_l * (1.f / B);
                out[1] = reg_l * (1.f / B);
            }
        }
    }
}

extern "C" void kernel_launch(void* const* d_in, const int* in_sizes, int n_in,
                              void* d_out, int out_size, void* d_ws, size_t ws_size,
                              hipStream_t stream) {
    const float* cls = (const float*)d_in[0];
    const float* reg = (const float*)d_in[1];
    const float* anc = (const float*)d_in[2];
    const float* ann = (const float*)d_in[3];
    float* out = (float*)d_out;
    float* accum = (float*)d_ws;

    (void)hipMemsetAsync(accum, 0, 40 * sizeof(float), stream);

    focal_main_kernel<<<dim3(NTOTB), TPB, 0, stream>>>(cls, reg, anc, ann, accum, out);
}

// Round 14
// 55.429 us; speedup vs baseline: 2.0769x; 1.0638x over previous
//
#include <hip/hip_runtime.h>

constexpr int B = 8;
constexpr int A = 49104;
constexpr int C = 90;
constexpr int M = 32;
constexpr float EPS_CLIP = 1e-4f;
constexpr float LN2 = 0.6931471805599453f;

constexpr int TPB = 256;
constexpr int N4_IMG = A * C / 4;                   // 1,104,840 float4 per image
constexpr int SB_PER_IMG = 270;                     // stream blocks per image
constexpr int STRIDE4 = SB_PER_IMG * TPB;           // 69,120 float4 inter-iteration stride
constexpr int NSTREAM = SB_PER_IMG * B;             // 2160
constexpr int APT = 4;                              // anchors per thread
constexpr int AB_ANCH = TPB * APT;                  // 1024 anchors per anchor-block
constexpr int ABPI = (A + AB_ANCH - 1) / AB_ANCH;   // 48 anchor-blocks per image
constexpr int NANCH = ABPI * B;                     // 384
constexpr int NTOTB = NANCH + NSTREAM;              // 2544 blocks

typedef float f32x4 __attribute__((ext_vector_type(4)));

// accum (d_ws): [0..B) S (log2 domain), [B..2B) corr, [2B..3B) reg_sum, [3B..4B) pos_cnt

__device__ __forceinline__ float clampp(float v) {
    return fminf(fmaxf(v, EPS_CLIP), 1.f - EPS_CLIP);   // v_med3_f32
}

__device__ __forceinline__ float neg4(f32x4 v) {
    float s = 0.f;
#pragma unroll
    for (int j = 0; j < 4; ++j) {
        const float p = clampp(v[j]);
        s = fmaf(p * p, __log2f(1.f - p), s);
    }
    return s;
}

__global__ __launch_bounds__(TPB) void focal_main_kernel(
    const float* __restrict__ cls,   // [B, A, C]
    const float* __restrict__ reg,   // [B, A, 4]
    const float* __restrict__ anc,   // [A, 4]
    const float* __restrict__ ann,   // [B, M, 5]
    float* __restrict__ accum)
{
    __shared__ float s_ann[M * 5];
    __shared__ float s_red[3][TPB / 64];
    __shared__ int   s_list[AB_ANCH];
    __shared__ int   s_cnt;

    const int t    = threadIdx.x;
    const int wid  = t >> 6;
    const int lane = t & 63;
    const int blk  = blockIdx.x;

    if (blk < NANCH) {
        // ===== Anchor blocks (grid FRONT: co-resident with streams) =====
        const int b     = blk / ABPI;
        const int abase = (blk - b * ABPI) * AB_ANCH;

        if (t < M * 5) s_ann[t] = ann[b * M * 5 + t];
        if (t == 0) s_cnt = 0;
        __syncthreads();

        float corr = 0.f, reg_sum = 0.f, pos_cnt = 0.f;

        float4 ab4[APT];
        float  awk[APT], ahk[APT], areaA[APT], best[APT];
        int    argm[APT];
        bool   act[APT];
#pragma unroll
        for (int k = 0; k < APT; ++k) {
            const int a = abase + t + k * TPB;
            act[k] = (a < A);
            ab4[k] = act[k] ? reinterpret_cast<const float4*>(anc)[a]
                            : make_float4(0.f, 0.f, 0.f, 0.f);
            awk[k] = ab4[k].z - ab4[k].x;
            ahk[k] = ab4[k].w - ab4[k].y;
            areaA[k] = awk[k] * ahk[k];
            best[k] = -INFINITY;
            argm[k] = 0;
        }

        for (int m = 0; m < M; ++m) {
            const float bx1 = s_ann[m * 5 + 0];
            const float by1 = s_ann[m * 5 + 1];
            const float bx2 = s_ann[m * 5 + 2];
            const float by2 = s_ann[m * 5 + 3];
            const float lab = s_ann[m * 5 + 4];
            const float areaB = (bx2 - bx1) * (by2 - by1);
            const bool  vgt = (lab != -1.0f);
#pragma unroll
            for (int k = 0; k < APT; ++k) {
                float iw = fminf(ab4[k].z, bx2) - fmaxf(ab4[k].x, bx1);
                float ih = fminf(ab4[k].w, by2) - fmaxf(ab4[k].y, by1);
                iw = fmaxf(iw, 0.f);
                ih = fmaxf(ih, 0.f);
                const float inter = iw * ih;
                const float ua = fmaxf(areaA[k] + areaB - inter, 1e-8f);
                const float iou = inter / ua;
                const float val = vgt ? iou : -1.0f;
                if (val > best[k]) { best[k] = val; argm[k] = m; }   // first argmax
            }
        }

#pragma unroll
        for (int k = 0; k < APT; ++k) {
            if (!act[k]) continue;
            const int a = abase + t + k * TPB;
            if (best[k] >= 0.5f) {
                pos_cnt += 1.f;
                const int am = argm[k];
                const float gx1 = s_ann[am * 5 + 0];
                const float gy1 = s_ann[am * 5 + 1];
                const float gx2 = s_ann[am * 5 + 2];
                const float gy2 = s_ann[am * 5 + 3];
                const float acx = ab4[k].x + 0.5f * awk[k];
                const float acy = ab4[k].y + 0.5f * ahk[k];
                const float gw0 = gx2 - gx1;
                const float gh0 = gy2 - gy1;
                const float gcx = gx1 + 0.5f * gw0;
                const float gcy = gy1 + 0.5f * gh0;
                const float gw = fmaxf(gw0, 1.f);
                const float gh = fmaxf(gh0, 1.f);
                const float4 rp = reinterpret_cast<const float4*>(reg)[(size_t)b * A + a];
                const float rt0 = (gcx - acx) / awk[k] * 10.f;
                const float rt1 = (gcy - acy) / ahk[k] * 10.f;
                const float rt2 = __logf(gw / awk[k]) * 5.f;
                const float rt3 = __logf(gh / ahk[k]) * 5.f;
                const float d0 = fabsf(rt0 - rp.x);
                const float d1 = fabsf(rt1 - rp.y);
                const float d2 = fabsf(rt2 - rp.z);
                const float d3 = fabsf(rt3 - rp.w);
                auto sl1 = [](float d) {
                    return (d <= (1.f / 9.f)) ? 4.5f * d * d : d - (0.5f / 9.f);
                };
                reg_sum += sl1(d0) + sl1(d1) + sl1(d2) + sl1(d3);

                const int cidx = (int)s_ann[am * 5 + 4];
                const float p = clampp(cls[((size_t)b * A + a) * C + cidx]);
                corr += 0.75f * LN2 * (p * p * __log2f(1.f - p))      // cancel streamed term
                      + 0.25f * (1.f - p) * (1.f - p) * (-__logf(p)); // true positive term
            } else if (best[k] >= 0.4f) {
                const int slot = atomicAdd(&s_cnt, 1);
                s_list[slot] = t + k * TPB;
            }
        }
        __syncthreads();

        // wave-cooperative coalesced row sums for ignore anchors
        const int cnt = s_cnt;
        for (int i = wid; i < cnt; i += TPB / 64) {
            const int aidx = s_list[i];
            const float* row = cls + ((size_t)b * A + abase + aidx) * (size_t)C;
            float s = 0.f;
            if (lane < C) {
                const float p = clampp(row[lane]);
                s = p * p * __log2f(1.f - p);
            }
            if (lane + 64 < C) {
                const float p = clampp(row[lane + 64]);
                s = fmaf(p * p, __log2f(1.f - p), s);
            }
            for (int off = 32; off; off >>= 1) s += __shfl_down(s, off);
            if (lane == 0) corr += 0.75f * LN2 * s;
        }

        float v0 = corr, v1 = reg_sum, v2 = pos_cnt;
        for (int off = 32; off; off >>= 1) {
            v0 += __shfl_down(v0, off);
            v1 += __shfl_down(v1, off);
            v2 += __shfl_down(v2, off);
        }
        if (lane == 0) { s_red[0][wid] = v0; s_red[1][wid] = v1; s_red[2][wid] = v2; }
        __syncthreads();
        if (t == 0) {
            float a0 = 0.f, a1 = 0.f, a2 = 0.f;
            for (int w = 0; w < TPB / 64; ++w) {
                a0 += s_red[0][w]; a1 += s_red[1][w]; a2 += s_red[2][w];
            }
            atomicAdd(&accum[B + b],     a0);
            atomicAdd(&accum[2 * B + b], a1);
            atomicAdd(&accum[3 * B + b], a2);
        }
    } else {
        // ===== Stream blocks: per-image GRID-STRIDE (probe shape, 1.08 MB stride) =====
        const int sblk = blk - NANCH;
        const int img  = sblk / SB_PER_IMG;
        const int jx   = sblk - img * SB_PER_IMG;
        const f32x4* __restrict__ ip =
            reinterpret_cast<const f32x4*>(cls) + (size_t)img * N4_IMG;
        const int base = jx * TPB + t;          // 0 .. 69119

        float accA = 0.f, accB = 0.f;
        f32x4 v[8];
        // batch 1: k = 0..7, always in bounds (base_max + 7*STRIDE4 < N4_IMG)
#pragma unroll
        for (int k = 0; k < 8; ++k) v[k] = ip[base + k * STRIDE4];
#pragma unroll
        for (int k = 0; k < 8; ++k) {
            if (k & 1) accB += neg4(v[k]); else accA += neg4(v[k]);
        }
        // batch 2: k = 8..15, only k=15 can run off the image end
#pragma unroll
        for (int k = 0; k < 8; ++k) {
            const int ix = base + (k + 8) * STRIDE4;
            v[k] = ip[ix < N4_IMG ? ix : 0];
        }
#pragma unroll
        for (int k = 0; k < 8; ++k) {
            const int ix = base + (k + 8) * STRIDE4;
            if (ix < N4_IMG) {
                if (k & 1) accB += neg4(v[k]); else accA += neg4(v[k]);
            }
        }

        float w0 = accA + accB;
        for (int off = 32; off; off >>= 1) w0 += __shfl_down(w0, off);
        if (lane == 0) s_red[0][wid] = w0;
        __syncthreads();
        if (t == 0) {
            float a0 = 0.f;
            for (int w = 0; w < TPB / 64; ++w) a0 += s_red[0][w];
            atomicAdd(&accum[img], a0);
        }
    }
}

// ---------------- Finalize (separate kernel; boundary orders the atomics) ----------------
__global__ void focal_finalize_kernel(const float* __restrict__ ann,
                                      const float* __restrict__ accum,
                                      float* __restrict__ out)
{
    const int t = threadIdx.x;
    float cls_l = 0.f, reg_l = 0.f;
    if (t < B) {
        bool has = false;
        for (int m = 0; m < M; ++m)
            has = has || (ann[t * M * 5 + m * 5 + 4] != -1.0f);
        const float S    = accum[t];
        const float corr = accum[B + t];
        const float rs   = accum[2 * B + t];
        const float np   = accum[3 * B + t];
        const float cls_sum = -0.75f * LN2 * S + corr;
        cls_l = has ? cls_sum / fmaxf(np, 1.f) : 0.f;
        reg_l = (has && np > 0.f) ? rs / fmaxf(np * 4.f, 1.f) : 0.f;
    }
    for (int off = 4; off; off >>= 1) {
        cls_l += __shfl_down(cls_l, off);
        reg_l += __shfl_down(reg_l, off);
    }
    if (t == 0) {
        out[0] = cls_l * (1.f / B);
        out[1] = reg_l * (1.f / B);
    }
}

extern "C" void kernel_launch(void* const* d_in, const int* in_sizes, int n_in,
                              void* d_out, int out_size, void* d_ws, size_t ws_size,
                              hipStream_t stream) {
    const float* cls = (const float*)d_in[0];
    const float* reg = (const float*)d_in[1];
    const float* anc = (const float*)d_in[2];
    const float* ann = (const float*)d_in[3];
    float* out = (float*)d_out;
    float* accum = (float*)d_ws;

    (void)hipMemsetAsync(accum, 0, 4 * B * sizeof(float), stream);

    focal_main_kernel<<<dim3(NTOTB), TPB, 0, stream>>>(cls, reg, anc, ann, accum);
    focal_finalize_kernel<<<1, 64, 0, stream>>>(ann, accum, out);
}

// Round 15
// 54.523 us; speedup vs baseline: 2.1114x; 1.0166x over previous
//
#include <hip/hip_runtime.h>

constexpr int B = 8;
constexpr int A = 49104;
constexpr int C = 90;
constexpr int M = 32;
constexpr float EPS_CLIP = 1e-4f;
constexpr float LN2 = 0.6931471805599453f;

constexpr int TPB = 256;
constexpr int N4_TOT = B * A * C / 4;               // 8,838,720 float4 total
constexpr int N4_IMG = A * C / 4;                   // 1,104,840 float4 per image
constexpr int SL4 = 4096;                           // float4 per stream slice (64 KB)
constexpr int NSTREAM = (N4_TOT + SL4 - 1) / SL4;   // 2158
constexpr int APT = 4;                              // anchors per thread
constexpr int AB_ANCH = TPB * APT;                  // 1024 anchors per anchor-block
constexpr int ABPI = (A + AB_ANCH - 1) / AB_ANCH;   // 48 anchor-blocks per image
constexpr int NANCH = ABPI * B;                     // 384

typedef float f32x4 __attribute__((ext_vector_type(4)));

// accum (d_ws): [0..B) S (log2 domain), [B..2B) corr, [2B..3B) reg_sum, [3B..4B) pos_cnt

__device__ __forceinline__ float clampp(float v) {
    return fminf(fmaxf(v, EPS_CLIP), 1.f - EPS_CLIP);   // v_med3_f32
}

__device__ __forceinline__ float neg4(f32x4 v) {
    float s = 0.f;
#pragma unroll
    for (int j = 0; j < 4; ++j) {
        const float p = clampp(v[j]);
        s = fmaf(p * p, __log2f(1.f - p), s);
    }
    return s;
}

__global__ __launch_bounds__(TPB) void focal_main_kernel(
    const float* __restrict__ cls,   // [B, A, C]
    const float* __restrict__ reg,   // [B, A, 4]
    const float* __restrict__ anc,   // [A, 4]
    const float* __restrict__ ann,   // [B, M, 5]
    float* __restrict__ accum)
{
    __shared__ float s_ann[M * 5];
    __shared__ float s_red[3][TPB / 64];
    __shared__ int   s_list[AB_ANCH];
    __shared__ int   s_cnt;

    const int t    = threadIdx.x;
    const int wid  = t >> 6;
    const int lane = t & 63;
    const int blk  = blockIdx.x;

    if (blk < NANCH) {
        // ===== Anchor blocks (grid FRONT: co-resident with streams; VALU hides under BW) =====
        const int b     = blk / ABPI;
        const int abase = (blk - b * ABPI) * AB_ANCH;

        if (t < M * 5) s_ann[t] = ann[b * M * 5 + t];
        if (t == 0) s_cnt = 0;
        __syncthreads();

        float corr = 0.f, reg_sum = 0.f, pos_cnt = 0.f;

        float4 ab4[APT];
        float  awk[APT], ahk[APT], areaA[APT], best[APT];
        int    argm[APT];
        bool   act[APT];
#pragma unroll
        for (int k = 0; k < APT; ++k) {
            const int a = abase + t + k * TPB;
            act[k] = (a < A);
            ab4[k] = act[k] ? reinterpret_cast<const float4*>(anc)[a]
                            : make_float4(0.f, 0.f, 0.f, 0.f);
            awk[k] = ab4[k].z - ab4[k].x;
            ahk[k] = ab4[k].w - ab4[k].y;
            areaA[k] = awk[k] * ahk[k];
            best[k] = -INFINITY;
            argm[k] = 0;
        }

        for (int m = 0; m < M; ++m) {
            const float bx1 = s_ann[m * 5 + 0];
            const float by1 = s_ann[m * 5 + 1];
            const float bx2 = s_ann[m * 5 + 2];
            const float by2 = s_ann[m * 5 + 3];
            const float lab = s_ann[m * 5 + 4];
            const float areaB = (bx2 - bx1) * (by2 - by1);
            const bool  vgt = (lab != -1.0f);
#pragma unroll
            for (int k = 0; k < APT; ++k) {
                float iw = fminf(ab4[k].z, bx2) - fmaxf(ab4[k].x, bx1);
                float ih = fminf(ab4[k].w, by2) - fmaxf(ab4[k].y, by1);
                iw = fmaxf(iw, 0.f);
                ih = fmaxf(ih, 0.f);
                const float inter = iw * ih;
                const float ua = fmaxf(areaA[k] + areaB - inter, 1e-8f);
                const float iou = inter / ua;
                const float val = vgt ? iou : -1.0f;
                if (val > best[k]) { best[k] = val; argm[k] = m; }   // first argmax
            }
        }

#pragma unroll
        for (int k = 0; k < APT; ++k) {
            if (!act[k]) continue;
            const int a = abase + t + k * TPB;
            if (best[k] >= 0.5f) {
                pos_cnt += 1.f;
                const int am = argm[k];
                const float gx1 = s_ann[am * 5 + 0];
                const float gy1 = s_ann[am * 5 + 1];
                const float gx2 = s_ann[am * 5 + 2];
                const float gy2 = s_ann[am * 5 + 3];
                const float acx = ab4[k].x + 0.5f * awk[k];
                const float acy = ab4[k].y + 0.5f * ahk[k];
                const float gw0 = gx2 - gx1;
                const float gh0 = gy2 - gy1;
                const float gcx = gx1 + 0.5f * gw0;
                const float gcy = gy1 + 0.5f * gh0;
                const float gw = fmaxf(gw0, 1.f);
                const float gh = fmaxf(gh0, 1.f);
                const float4 rp = reinterpret_cast<const float4*>(reg)[(size_t)b * A + a];
                const float rt0 = (gcx - acx) / awk[k] * 10.f;
                const float rt1 = (gcy - acy) / ahk[k] * 10.f;
                const float rt2 = __logf(gw / awk[k]) * 5.f;
                const float rt3 = __logf(gh / ahk[k]) * 5.f;
                const float d0 = fabsf(rt0 - rp.x);
                const float d1 = fabsf(rt1 - rp.y);
                const float d2 = fabsf(rt2 - rp.z);
                const float d3 = fabsf(rt3 - rp.w);
                auto sl1 = [](float d) {
                    return (d <= (1.f / 9.f)) ? 4.5f * d * d : d - (0.5f / 9.f);
                };
                reg_sum += sl1(d0) + sl1(d1) + sl1(d2) + sl1(d3);

                const int cidx = (int)s_ann[am * 5 + 4];
                const float p = clampp(cls[((size_t)b * A + a) * C + cidx]);
                corr += 0.75f * LN2 * (p * p * __log2f(1.f - p))      // cancel streamed term
                      + 0.25f * (1.f - p) * (1.f - p) * (-__logf(p)); // true positive term
            } else if (best[k] >= 0.4f) {
                const int slot = atomicAdd(&s_cnt, 1);
                s_list[slot] = t + k * TPB;
            }
        }
        __syncthreads();

        // wave-cooperative coalesced row sums for ignore anchors
        const int cnt = s_cnt;
        for (int i = wid; i < cnt; i += TPB / 64) {
            const int aidx = s_list[i];
            const float* row = cls + ((size_t)b * A + abase + aidx) * (size_t)C;
            float s = 0.f;
            if (lane < C) {
                const float p = clampp(row[lane]);
                s = p * p * __log2f(1.f - p);
            }
            if (lane + 64 < C) {
                const float p = clampp(row[lane + 64]);
                s = fmaf(p * p, __log2f(1.f - p), s);
            }
            for (int off = 32; off; off >>= 1) s += __shfl_down(s, off);
            if (lane == 0) corr += 0.75f * LN2 * s;
        }

        float v0 = corr, v1 = reg_sum, v2 = pos_cnt;
        for (int off = 32; off; off >>= 1) {
            v0 += __shfl_down(v0, off);
            v1 += __shfl_down(v1, off);
            v2 += __shfl_down(v2, off);
        }
        if (lane == 0) { s_red[0][wid] = v0; s_red[1][wid] = v1; s_red[2][wid] = v2; }
        __syncthreads();
        if (t == 0) {
            float a0 = 0.f, a1 = 0.f, a2 = 0.f;
            for (int w = 0; w < TPB / 64; ++w) {
                a0 += s_red[0][w]; a1 += s_red[1][w]; a2 += s_red[2][w];
            }
            atomicAdd(&accum[B + b],     a0);
            atomicAdd(&accum[2 * B + b], a1);
            atomicAdd(&accum[3 * B + b], a2);
        }
    } else {
        // ===== Stream blocks (uniform 64 KB contiguous slices) =====
        const int sblk = blk - NANCH;
        const f32x4* __restrict__ cls4 = reinterpret_cast<const f32x4*>(cls);
        const int sbase = sblk * SL4;
        const int nsl   = min(SL4, N4_TOT - sbase);
        const int img0  = sbase / N4_IMG;
        const int imgL  = (sbase + nsl - 1) / N4_IMG;

        float acc0 = 0.f, acc1 = 0.f;
        if (img0 == imgL) {
            const f32x4* p = cls4 + sbase + t;
            int i = t;
            float accA = 0.f, accB = 0.f;
            for (; i + 7 * TPB < nsl; i += 8 * TPB) {
                f32x4 v[8];
#pragma unroll
                for (int k = 0; k < 8; ++k) v[k] = p[k * TPB];
                p += 8 * TPB;
#pragma unroll
                for (int k = 0; k < 8; ++k) {
                    if (k & 1) accB += neg4(v[k]); else accA += neg4(v[k]);
                }
            }
            for (; i < nsl; i += TPB) { accA += neg4(*p); p += TPB; }
            acc0 = accA + accB;
        } else {
            // image-boundary slice (7 of 2158)
            const int split = (img0 + 1) * N4_IMG;
            for (int i = t; i < nsl; i += TPB) {
                const float s = neg4(cls4[sbase + i]);
                if (sbase + i < split) acc0 += s; else acc1 += s;
            }
        }

        float w0 = acc0, w1 = acc1;
        for (int off = 32; off; off >>= 1) {
            w0 += __shfl_down(w0, off);
            w1 += __shfl_down(w1, off);
        }
        if (lane == 0) { s_red[0][wid] = w0; s_red[1][wid] = w1; }
        __syncthreads();
        if (t == 0) {
            float a0 = 0.f, a1 = 0.f;
            for (int w = 0; w < TPB / 64; ++w) { a0 += s_red[0][w]; a1 += s_red[1][w]; }
            atomicAdd(&accum[img0], a0);
            if (imgL != img0) atomicAdd(&accum[imgL], a1);
        }
    }
}

// ---------------- Finalize (separate kernel; boundary orders the atomics) ----------------
__global__ void focal_finalize_kernel(const float* __restrict__ ann,
                                      const float* __restrict__ accum,
                                      float* __restrict__ out)
{
    const int t = threadIdx.x;
    float cls_l = 0.f, reg_l = 0.f;
    if (t < B) {
        bool has = false;
        for (int m = 0; m < M; ++m)
            has = has || (ann[t * M * 5 + m * 5 + 4] != -1.0f);
        const float S    = accum[t];
        const float corr = accum[B + t];
        const float rs   = accum[2 * B + t];
        const float np   = accum[3 * B + t];
        const float cls_sum = -0.75f * LN2 * S + corr;
        cls_l = has ? cls_sum / fmaxf(np, 1.f) : 0.f;
        reg_l = (has && np > 0.f) ? rs / fmaxf(np * 4.f, 1.f) : 0.f;
    }
    for (int off = 4; off; off >>= 1) {
        cls_l += __shfl_down(cls_l, off);
        reg_l += __shfl_down(reg_l, off);
    }
    if (t == 0) {
        out[0] = cls_l * (1.f / B);
        out[1] = reg_l * (1.f / B);
    }
}

extern "C" void kernel_launch(void* const* d_in, const int* in_sizes, int n_in,
                              void* d_out, int out_size, void* d_ws, size_t ws_size,
                              hipStream_t stream) {
    const float* cls = (const float*)d_in[0];
    const float* reg = (const float*)d_in[1];
    const float* anc = (const float*)d_in[2];
    const float* ann = (const float*)d_in[3];
    float* out = (float*)d_out;
    float* accum = (float*)d_ws;

    (void)hipMemsetAsync(accum, 0, 4 * B * sizeof(float), stream);

    focal_main_kernel<<<dim3(NANCH + NSTREAM), TPB, 0, stream>>>(cls, reg, anc, ann, accum);
    focal_finalize_kernel<<<1, 64, 0, stream>>>(ann, accum, out);
}